// Round 8
// baseline (4214.175 us; speedup 1.0000x reference)
//
#include <hip/hip_runtime.h>
#include <hip/hip_cooperative_groups.h>

// VanillaRNNLayer: B=32, T=2048, I=512, H=512 — ALL FP32.
//   phase 1: xp = x @ Wx^T + bx + bh   -> fp32 into d_out (consumed in place)
//   phase 2: h_t = tanh(xp_t + Wh h_{t-1}), 8 blocks/chain, Wh slice in regs.
// R7 analysis: step time ~3100cy, dominated by IC round-trip of the qword
// exchange (publish sc1 -> poll sc1 ~ 1200-1500cy). R8: verify all 8 parts
// of a chain share an XCD (HW_REG_XCC_ID + grid.sync), then poll via
// L2-served sc0 loads (~200cy) with a bounded sc1 backstop (correct even if
// sc0 serves stale lines). Publisher always stores sc1 (IC always current).

constexpr int Bb = 32, Tt = 2048, Ii = 512, Hh = 512;
constexpr int NP = 8;            // parts (blocks) per chain
constexpr int RP = Hh / NP;      // 64 rows per part

static __device__ __forceinline__ float fast_tanh(float x) {
    float ax = fabsf(x);
    float e = __expf(-2.0f * ax);            // in (0,1], no overflow
    float r = (1.0f - e) / (1.0f + e);
    return copysignf(r, x);
}

// ---------------- Phase 1: xp GEMM, 128x128 tile, 8x8/thread ----------------
// Measured ~0.34 ms ~= fp32 vector roofline for 34.4 GFLOP — done.
__global__ __launch_bounds__(256, 2)
void xproj_gemm(const float* __restrict__ x, const float* __restrict__ Wx,
                const float* __restrict__ bx, const float* __restrict__ bh,
                float* __restrict__ xp)
{
    constexpr int BM = 128, BK = 16, LDT = BM + 4;   // [k][m] transposed tiles
    __shared__ float As[BK][LDT];
    __shared__ float Bs[BK][LDT];

    const int tid = threadIdx.x;
    const int m0 = blockIdx.x * BM;
    const int n0 = blockIdx.y * BM;
    const int lrow = tid >> 1;               // 0..127
    const int lkh  = (tid & 1) * 8;          // 0 or 8
    const int tx = tid & 15, ty = tid >> 4;

    float acc[2][2][4][4] = {};

    for (int k0 = 0; k0 < Ii; k0 += BK) {
        float4 a0 = *reinterpret_cast<const float4*>(&x[(size_t)(m0 + lrow) * Ii + k0 + lkh]);
        float4 a1 = *reinterpret_cast<const float4*>(&x[(size_t)(m0 + lrow) * Ii + k0 + lkh + 4]);
        float4 b0 = *reinterpret_cast<const float4*>(&Wx[(size_t)(n0 + lrow) * Ii + k0 + lkh]);
        float4 b1 = *reinterpret_cast<const float4*>(&Wx[(size_t)(n0 + lrow) * Ii + k0 + lkh + 4]);
        __syncthreads();
        As[lkh + 0][lrow] = a0.x; As[lkh + 1][lrow] = a0.y;
        As[lkh + 2][lrow] = a0.z; As[lkh + 3][lrow] = a0.w;
        As[lkh + 4][lrow] = a1.x; As[lkh + 5][lrow] = a1.y;
        As[lkh + 6][lrow] = a1.z; As[lkh + 7][lrow] = a1.w;
        Bs[lkh + 0][lrow] = b0.x; Bs[lkh + 1][lrow] = b0.y;
        Bs[lkh + 2][lrow] = b0.z; Bs[lkh + 3][lrow] = b0.w;
        Bs[lkh + 4][lrow] = b1.x; Bs[lkh + 5][lrow] = b1.y;
        Bs[lkh + 6][lrow] = b1.z; Bs[lkh + 7][lrow] = b1.w;
        __syncthreads();
        #pragma unroll
        for (int k = 0; k < BK; ++k) {
            float4 av[2], bv[2];
            av[0] = *reinterpret_cast<const float4*>(&As[k][ty * 4]);
            av[1] = *reinterpret_cast<const float4*>(&As[k][64 + ty * 4]);
            bv[0] = *reinterpret_cast<const float4*>(&Bs[k][tx * 4]);
            bv[1] = *reinterpret_cast<const float4*>(&Bs[k][64 + tx * 4]);
            #pragma unroll
            for (int rh = 0; rh < 2; ++rh) {
                const float* ap = reinterpret_cast<const float*>(&av[rh]);
                #pragma unroll
                for (int ch = 0; ch < 2; ++ch) {
                    const float* bp = reinterpret_cast<const float*>(&bv[ch]);
                    #pragma unroll
                    for (int i = 0; i < 4; ++i)
                        #pragma unroll
                        for (int j = 0; j < 4; ++j)
                            acc[rh][ch][i][j] += ap[i] * bp[j];
                }
            }
        }
    }

    float4 bias[2];
    #pragma unroll
    for (int ch = 0; ch < 2; ++ch) {
        int cb = n0 + ch * 64 + tx * 4;
        bias[ch] = make_float4(bx[cb] + bh[cb], bx[cb + 1] + bh[cb + 1],
                               bx[cb + 2] + bh[cb + 2], bx[cb + 3] + bh[cb + 3]);
    }
    #pragma unroll
    for (int rh = 0; rh < 2; ++rh)
        #pragma unroll
        for (int i = 0; i < 4; ++i) {
            size_t row = (size_t)(m0 + rh * 64 + ty * 4 + i);
            #pragma unroll
            for (int ch = 0; ch < 2; ++ch) {
                const float* bp = reinterpret_cast<const float*>(&bias[ch]);
                float4 v = make_float4(acc[rh][ch][i][0] + bp[0], acc[rh][ch][i][1] + bp[1],
                                       acc[rh][ch][i][2] + bp[2], acc[rh][ch][i][3] + bp[3]);
                *reinterpret_cast<float4*>(&xp[row * Hh + n0 + ch * 64 + tx * 4]) = v;
            }
        }
}

// ---------------- zero xbuf (every launch; kernel-end writeback -> IC) ------
__global__ void zero_xbuf(unsigned long long* __restrict__ xb)
{
    xb[(size_t)blockIdx.x * 512 + threadIdx.x] = 0ull;   // 64 blocks x 512
}

// ---------------- Phase 2: scan, 8 blocks/chain, L2-local qword exchange ----
// bid: chain c = bid&31, part P = bid>>5 (parts of a chain share bid%8 ->
// same XCD under round-robin; VERIFIED at runtime, not assumed).
// Wave w, lane (hf,lp): rows P*64 + w*8 + hf*4 + s, cols q*128 + lp*4 + i.
// Wave P = finisher; waves w!=P poll part w's {tag,val} qwords.
__global__ __launch_bounds__(512, 1)
void rnn_scan_mb(const float* __restrict__ Wh, const float* __restrict__ h0,
                 float* __restrict__ out, unsigned long long* __restrict__ xbuf,
                 unsigned int* __restrict__ xcc_arr)
{
    const int bid = blockIdx.x;
    const int c = bid & 31;
    const int P = bid >> 5;
    const int tid = threadIdx.x;
    const int w = tid >> 6;          // wave 0..7
    const int lane = tid & 63;
    const int hf = lane >> 5, lp = lane & 31;
    const int lrow0 = w * 8 + hf * 4;          // local row base 0..60

    __shared__ __align__(16) float hs[Hh];
    __shared__ __align__(16) float pacc[RP][36];   // [local row][lp]
    __shared__ unsigned int same_sh;

    // ---- publish this block's XCD id (agent atomic -> IC) ----
    unsigned int myxcc;
    asm volatile("s_getreg_b32 %0, hwreg(20, 0, 32)" : "=s"(myxcc));  // HW_REG_XCC_ID
    if (tid == 0)
        __hip_atomic_store(&xcc_arr[bid], myxcc, __ATOMIC_RELAXED,
                           __HIP_MEMORY_SCOPE_AGENT);

    // ---- weights -> registers via opaque asm loads (no remat possible) ----
    float4 wreg[4][4];
    #pragma unroll
    for (int s = 0; s < 4; ++s)
        #pragma unroll
        for (int q = 0; q < 4; ++q) {
            const float* ap = &Wh[(size_t)(P * RP + lrow0 + s) * Hh + q * 128 + lp * 4];
            asm volatile("global_load_dwordx4 %0, %1, off"
                         : "=v"(wreg[s][q]) : "v"(ap));
        }
    asm volatile("s_waitcnt vmcnt(0)" ::: "memory");

    hs[tid] = h0[(size_t)c * Hh + tid];

    float* ob = out + (size_t)c * Tt * Hh;                // xp -> h in place
    unsigned long long* xb = xbuf + (size_t)c * 2 * Hh;   // [slot][row]

    float xp_cur = 0.f;
    if (w == P) xp_cur = ob[P * RP + lane];               // finisher: xp row t=0

    // ---- all xcc ids published; check chain locality ----
    cooperative_groups::this_grid().sync();
    if (tid == 0) {
        unsigned int s = 1;
        for (int p = 0; p < NP; ++p)
            s &= (__hip_atomic_load(&xcc_arr[(p << 5) | c], __ATOMIC_RELAXED,
                                    __HIP_MEMORY_SCOPE_AGENT) == myxcc) ? 1u : 0u;
        same_sh = s;
    }
    __syncthreads();                                      // also covers hs readiness
    const bool samexcd = (same_sh != 0);

    for (int t = 0; t < Tt; ++t) {
        // prefetch next xp early (off the finish critical path)
        float xp_nxt = 0.f;
        if (w == P && t + 1 < Tt) xp_nxt = ob[(size_t)(t + 1) * Hh + P * RP + lane];

        // ---- FMA: 4 rows x 16 interleaved cols per thread
        float4 hv[4];
        #pragma unroll
        for (int q = 0; q < 4; ++q)
            hv[q] = *reinterpret_cast<const float4*>(&hs[q * 128 + lp * 4]);
        #pragma unroll
        for (int s = 0; s < 4; ++s) {
            float sum = 0.f;
            #pragma unroll
            for (int q = 0; q < 4; ++q) {
                const float* wq = reinterpret_cast<const float*>(&wreg[s][q]);
                const float* hq = reinterpret_cast<const float*>(&hv[q]);
                sum += wq[0] * hq[0]; sum += wq[1] * hq[1];
                sum += wq[2] * hq[2]; sum += wq[3] * hq[3];
            }
            pacc[lrow0 + s][lp] = sum;
        }
        __syncthreads();                 // B-mid: pacc ready; hs reads done

        if (w == P) {
            // ---- finisher: row = P*64 + lane
            float ssum = xp_cur;
            #pragma unroll
            for (int q = 0; q < 8; ++q) {
                float4 p4 = *reinterpret_cast<const float4*>(&pacc[lane][q * 4]);
                ssum += (p4.x + p4.y) + (p4.z + p4.w);
            }
            float hval = fast_tanh(ssum);
            if (t + 1 < Tt) {
                unsigned long long msg =
                    ((unsigned long long)(unsigned)(t + 1) << 32) |
                    (unsigned long long)__float_as_uint(hval);
                unsigned long long* pa = &xb[(size_t)(t & 1) * Hh + P * RP + lane];
                // publish FIRST (sc1 write-through: L2 updated + IC current)
                asm volatile("global_store_dwordx2 %0, %1, off sc1"
                             :: "v"(pa), "v"(msg) : "memory");
                ob[(size_t)t * Hh + P * RP + lane] = hval;
                hs[P * RP + lane] = hval;
                xp_cur = xp_nxt;
            } else {
                ob[(size_t)t * Hh + P * RP + lane] = hval;
                out[(size_t)Bb * Tt * Hh + (size_t)c * Hh + P * RP + lane] = hval;
            }
        } else if (t + 1 < Tt) {
            // ---- poll part w's qword: data IS the flag
            const unsigned int want = (unsigned)(t + 1);
            const unsigned long long* pa = &xb[(size_t)(t & 1) * Hh + w * RP + lane];
            unsigned long long msg;
            bool got = false;
            while (!got) {
                if (samexcd) {
                    // fast: L1-bypass, L2-served (parts share this XCD's L2)
                    #pragma unroll 1
                    for (int it = 0; it < 8; ++it) {
                        asm volatile("global_load_dwordx2 %0, %1, off sc0\n\t"
                                     "s_waitcnt vmcnt(0)"
                                     : "=v"(msg) : "v"(pa) : "memory");
                        if ((unsigned)(msg >> 32) == want) { got = true; break; }
                    }
                    if (got) break;
                }
                // backstop / cross-XCD path: device-coherent load (IC)
                asm volatile("global_load_dwordx2 %0, %1, off sc0 sc1\n\t"
                             "s_waitcnt vmcnt(0)"
                             : "=v"(msg) : "v"(pa) : "memory");
                got = ((unsigned)(msg >> 32) == want);
            }
            hs[w * RP + lane] = __uint_as_float((unsigned)msg);
        }
        __syncthreads();                 // B-end: hs = h(t) ready
    }
}

// ---------------- Fallback single-block scan (tiny ws) ----------------
__global__ __launch_bounds__(512)
void rnn_scan_sb(const float* __restrict__ W, const float* __restrict__ h0,
                 float* __restrict__ out)
{
    const int b = blockIdx.x;
    const int j = threadIdx.x;
    __shared__ float hsb[2][Hh];
    hsb[0][j] = h0[(size_t)b * Hh + j];
    __syncthreads();

    float* ob = out + (size_t)b * Tt * Hh;
    const float* wbase = W + (size_t)j * Hh;

    float xp_cur = ob[j];
    int cur = 0;
    for (int t = 0; t < Tt; ++t) {
        float xp_next = (t + 1 < Tt) ? ob[(size_t)(t + 1) * Hh + j] : 0.0f;
        float4 a = make_float4(xp_cur, 0.0f, 0.0f, 0.0f);
        const float* h = hsb[cur];
        #pragma unroll 8
        for (int c4 = 0; c4 < Hh / 4; ++c4) {
            float4 wv = *reinterpret_cast<const float4*>(&wbase[c4 * 4]);
            float4 hv = *reinterpret_cast<const float4*>(&h[c4 * 4]);
            a.x += wv.x * hv.x; a.y += wv.y * hv.y;
            a.z += wv.z * hv.z; a.w += wv.w * hv.w;
        }
        float hn = tanhf((a.x + a.y) + (a.z + a.w));
        hsb[cur ^ 1][j] = hn;
        ob[(size_t)t * Hh + j] = hn;
        xp_cur = xp_next;
        cur ^= 1;
        __syncthreads();
    }
    out[(size_t)Bb * Tt * Hh + (size_t)b * Hh + j] = hsb[cur][j];
}

extern "C" void kernel_launch(void* const* d_in, const int* in_sizes, int n_in,
                              void* d_out, int out_size, void* d_ws, size_t ws_size,
                              hipStream_t stream)
{
    const float* x  = (const float*)d_in[0];
    const float* h0 = (const float*)d_in[1];
    const float* Wx = (const float*)d_in[2];
    const float* bx = (const float*)d_in[3];
    const float* Wh = (const float*)d_in[4];
    const float* bh = (const float*)d_in[5];
    float* out = (float*)d_out;

    dim3 g1(Bb * Tt / 128, Hh / 128);     // (512, 4)
    xproj_gemm<<<g1, 256, 0, stream>>>(x, Wx, bx, bh, out);

    const size_t xb_bytes  = (size_t)Bb * 2 * Hh * sizeof(unsigned long long); // 256 KB
    const size_t xcc_bytes = 256 * sizeof(unsigned int);                       // 1 KB
    if (ws_size >= xb_bytes + xcc_bytes) {
        unsigned long long* xbuf = (unsigned long long*)d_ws;
        unsigned int* xcc_arr = (unsigned int*)((char*)d_ws + xb_bytes);
        zero_xbuf<<<64, 512, 0, stream>>>(xbuf);
        void* args[] = {(void*)&Wh, (void*)&h0, (void*)&out, (void*)&xbuf, (void*)&xcc_arr};
        hipLaunchCooperativeKernel((void*)rnn_scan_mb, dim3(NP * Bb), dim3(512),
                                   args, 0, stream);
    } else {
        rnn_scan_sb<<<Bb, Hh, 0, stream>>>(Wh, h0, out);
    }
}